// Round 1
// baseline (233.219 us; speedup 1.0000x reference)
//
#include <hip/hip_runtime.h>
#include <type_traits>
#include <utility>

#define B_ 2
#define S_ 2048
#define D_ 1024
#define H_ 16
#define HD_ 64
#define KDIM 1024

typedef __attribute__((ext_vector_type(8))) short    s16x8;
typedef __attribute__((ext_vector_type(8))) _Float16 h16x8;
typedef __attribute__((ext_vector_type(4))) float    f32x4;
typedef __attribute__((ext_vector_type(4))) int      i32x4;
typedef __attribute__((ext_vector_type(2))) int      i32x2;

// --- MFMA operand-type hedge (fp16) ---
template <typename T, typename = void> struct mfma_takes : std::false_type {};
template <typename T>
struct mfma_takes<T, std::void_t<decltype(__builtin_amdgcn_mfma_f32_16x16x32_f16(
    std::declval<T>(), std::declval<T>(), std::declval<f32x4>(), 0, 0, 0))>>
    : std::true_type {};
using frag8 = std::conditional_t<mfma_takes<h16x8>::value, h16x8, s16x8>;

__device__ __forceinline__ f32x4 mfma_f16(frag8 a, frag8 b, f32x4 c) {
  return __builtin_amdgcn_mfma_f32_16x16x32_f16(a, b, c, 0, 0, 0);
}

__device__ __forceinline__ short f2h(float f) {  // RTNE f32 -> fp16 bits
  _Float16 h = (_Float16)f;
  short s; __builtin_memcpy(&s, &h, 2);
  return s;
}
__device__ __forceinline__ int pk2h(float a, float b) {  // v_cvt_pkrtz 2xfp16
  auto p = __builtin_amdgcn_cvt_pkrtz(a, b);   // __fp16 ext_vector(2)
  int r; __builtin_memcpy(&r, &p, 4); return r;
}
__device__ __forceinline__ frag8 ld_frag(const short* p) {
  return __builtin_bit_cast(frag8, *(const i32x4*)p);
}
__device__ __forceinline__ float fast_exp2(float x) {
  return __builtin_amdgcn_exp2f(x);
}

typedef __attribute__((address_space(1))) const void gvoid;
typedef __attribute__((address_space(3))) void lvoid;
__device__ __forceinline__ void async_copy16(const void* g, void* l) {
  __builtin_amdgcn_global_load_lds((gvoid*)g, (lvoid*)l, 16, 0, 0);
}

#define RAW_BARRIER() asm volatile("s_barrier" ::: "memory")
#define WAITCNT_VM(n) asm volatile("s_waitcnt vmcnt(" #n ")" ::: "memory")

// ---------------------------------------------------------------------------
// Fused fp32 -> fp16 converts: q,k,v (2048 blocks each) + 4 weights (512 each)
// ---------------------------------------------------------------------------
__global__ __launch_bounds__(256)
void conv_all(const float* __restrict__ q, const float* __restrict__ k,
              const float* __restrict__ v, const float* __restrict__ Wq,
              const float* __restrict__ Wk, const float* __restrict__ Wv,
              const float* __restrict__ Wo,
              short* __restrict__ qh, short* __restrict__ kh,
              short* __restrict__ vh, short* __restrict__ wq,
              short* __restrict__ wk, short* __restrict__ wv,
              short* __restrict__ wo) {
  const int blk = blockIdx.x;
  const float* src; short* dst; int base;
  if (blk < 2048)      { src = q;  dst = qh; base = blk; }
  else if (blk < 4096) { src = k;  dst = kh; base = blk - 2048; }
  else if (blk < 6144) { src = v;  dst = vh; base = blk - 4096; }
  else if (blk < 6656) { src = Wq; dst = wq; base = blk - 6144; }
  else if (blk < 7168) { src = Wk; dst = wk; base = blk - 6656; }
  else if (blk < 7680) { src = Wv; dst = wv; base = blk - 7168; }
  else                 { src = Wo; dst = wo; base = blk - 7680; }
  const int i = base * 2048 + threadIdx.x * 8;
  float4 a0 = *(const float4*)(src + i);
  float4 a1 = *(const float4*)(src + i + 4);
  short h[8] = { f2h(a0.x), f2h(a0.y), f2h(a0.z), f2h(a0.w),
                 f2h(a1.x), f2h(a1.y), f2h(a1.z), f2h(a1.w) };
  i32x4 ph; __builtin_memcpy(&ph, h, 16);
  *(i32x4*)(dst + i) = ph;
}

// ---------------------------------------------------------------------------
// QKV projection GEMM, fp16 A & W, tile 128x128, BK=32, triple-buffered
// global_load_lds (prefetch distance 2). A-GROUPED XCD DECODE: all 8 bn
// blocks sharing one A-tile (z,bm) land on the same XCD (xcd = p&7 via
// p=(i>>3)*8+xcd), so each A tile is L2-filled once.
// ---------------------------------------------------------------------------
__global__ __launch_bounds__(256, 3)
void gemm_qkv(const short* __restrict__ qh, const short* __restrict__ kh,
              const short* __restrict__ vh, const short* __restrict__ wq,
              const short* __restrict__ wk, const short* __restrict__ wv,
              const float* __restrict__ bq, const float* __restrict__ bk,
              const float* __restrict__ bv, short* __restrict__ Qf,
              short* __restrict__ Kf, short* __restrict__ Vt, float QS) {
  __shared__ short As[3 * 4096];
  __shared__ short Bs[3 * 4096];

  const int blk = blockIdx.x;
  const int xcd = blk & 7, i = blk >> 3;      // i in [0,96)
  const int p = (i >> 3) * 8 + xcd;           // A-tile id, p ≡ xcd (mod 8)
  const int bn = i & 7;
  const int z = p >> 5, bm = p & 31;
  const short* Ap = z == 0 ? qh : z == 1 ? kh : vh;
  const short* Wp = z == 0 ? wq : z == 1 ? wk : wv;
  const float* bias = z == 0 ? bq : z == 1 ? bk : bv;
  short* Out = z == 0 ? Qf : z == 1 ? Kf : Vt;
  const float scale = z == 0 ? QS : 1.0f;
  const int omode = z == 2 ? 2 : 1;

  const int t = threadIdx.x, wave = t >> 6, lane = t & 63;
  const int laneN = lane & 15, quad = lane >> 4;
  const int wm = wave & 1, wn = wave >> 1;

  f32x4 acc[4][4];
#pragma unroll
  for (int i2 = 0; i2 < 4; ++i2)
#pragma unroll
    for (int j = 0; j < 4; ++j)
#pragma unroll
      for (int r = 0; r < 4; ++r) acc[i2][j][r] = 0.f;

  auto stage = [&](int buf, int kk) {   // 4 asyncs/thread per call
#pragma unroll
    for (int j = 0; j < 2; ++j) {
      const int chunk = j * 256 + t;
      const int row = chunk >> 2;
      const int gg = (chunk & 3) ^ ((row >> 1) & 3);
      async_copy16(Ap + (size_t)(bm * 128 + row) * KDIM + kk + gg * 8,
                   As + buf * 4096 + chunk * 8);
      async_copy16(Wp + (size_t)(bn * 128 + row) * KDIM + kk + gg * 8,
                   Bs + buf * 4096 + chunk * 8);
    }
  };

  stage(0, 0);
  stage(1, 32);
  int buf = 0;
  for (int kk = 0; kk < KDIM; kk += 32) {
    if (kk + 64 < KDIM) {
      int nb = buf + 2; if (nb >= 3) nb -= 3;
      stage(nb, kk + 64);
      WAITCNT_VM(8);        // drain current tile (oldest 4 of 12)
    } else if (kk + 32 < KDIM) {
      WAITCNT_VM(4);
    } else {
      WAITCNT_VM(0);
    }
    RAW_BARRIER();

    frag8 aF[4], bF[4];
#pragma unroll
    for (int mi = 0; mi < 4; ++mi) {
      const int row = wm * 64 + mi * 16 + laneN;
      aF[mi] = ld_frag(As + buf * 4096 + row * 32 +
                       ((quad ^ ((row >> 1) & 3)) * 8));
    }
#pragma unroll
    for (int ni = 0; ni < 4; ++ni) {
      const int row = wn * 64 + ni * 16 + laneN;
      bF[ni] = ld_frag(Bs + buf * 4096 + row * 32 +
                       ((quad ^ ((row >> 1) & 3)) * 8));
    }
#pragma unroll
    for (int mi = 0; mi < 4; ++mi)
#pragma unroll
      for (int ni = 0; ni < 4; ++ni)
        acc[mi][ni] = mfma_f16(aF[mi], bF[ni], acc[mi][ni]);
    RAW_BARRIER();
    buf = buf + 1 == 3 ? 0 : buf + 1;
  }

  // Epilogue. C/D: col = lane&15, row = quad*4 + reg.
#pragma unroll
  for (int mi = 0; mi < 4; ++mi)
#pragma unroll
    for (int ni = 0; ni < 4; ++ni) {
      const int colg = bn * 128 + wn * 64 + ni * 16 + laneN;
      const float bb = bias[colg];
      if (omode == 2) {
        // Vt [B,H,Hd,S]: r -> 4 consecutive s, same hd -> one b64 store
        const int rowg0 = bm * 128 + wm * 64 + mi * 16 + quad * 4;
        const int b = rowg0 >> 11, s0 = rowg0 & 2047;
        const int h = colg >> 6, hd = colg & 63;
        short pk[4];
#pragma unroll
        for (int r = 0; r < 4; ++r) pk[r] = f2h(acc[mi][ni][r] + bb);
        i32x2 w; __builtin_memcpy(&w, pk, 8);
        *(i32x2*)(Vt + (((size_t)(b * H_ + h)) * HD_ + hd) * S_ + s0) = w;
      } else {
#pragma unroll
        for (int r = 0; r < 4; ++r) {
          const int rowg = bm * 128 + wm * 64 + mi * 16 + quad * 4 + r;
          const int b = rowg >> 11, s = rowg & 2047;
          const int h = colg >> 6, hd = colg & 63;
          Out[(((size_t)(b * H_ + h)) * S_ + s) * HD_ + hd] =
              f2h((acc[mi][ni][r] + bb) * scale);
        }
      }
    }
}

// ---------------------------------------------------------------------------
// O projection: fp16 A x fp16 Wo -> fp32. Tile 128(M)x64(N), triple-buffered
// prefetch distance 2. A-GROUPED XCD DECODE: all 16 bn blocks sharing one
// A-tile (bm) on the same XCD (bm ≡ xcd mod 8); Wo (2 MB) fits per-XCD L2.
// ---------------------------------------------------------------------------
__global__ __launch_bounds__(256, 3)
void gemm_out(const short* __restrict__ Ap, const short* __restrict__ Wp,
              const float* __restrict__ bias, float* __restrict__ Out) {
  __shared__ short As[3 * 4096];   // 128x32
  __shared__ short Bs[3 * 2048];   // 64x32
  const int blk = blockIdx.x;
  const int xcd = blk & 7, i = blk >> 3;      // i in [0,64)
  const int bm = (i >> 4) * 8 + xcd;          // bm ≡ xcd (mod 8)
  const int bn = i & 15;

  const int t = threadIdx.x, wave = t >> 6, lane = t & 63;
  const int laneN = lane & 15, quad = lane >> 4;
  const int wm = wave & 1, wn = wave >> 1;

  f32x4 acc[4][2];
#pragma unroll
  for (int i2 = 0; i2 < 4; ++i2)
#pragma unroll
    for (int j = 0; j < 2; ++j)
#pragma unroll
      for (int r = 0; r < 4; ++r) acc[i2][j][r] = 0.f;

  auto stage = [&](int buf, int kk) {   // 3 asyncs/thread per call
#pragma unroll
    for (int j = 0; j < 2; ++j) {
      const int chunk = j * 256 + t;
      const int row = chunk >> 2;
      const int gg = (chunk & 3) ^ ((row >> 1) & 3);
      async_copy16(Ap + (size_t)(bm * 128 + row) * KDIM + kk + gg * 8,
                   As + buf * 4096 + chunk * 8);
    }
    {
      const int chunk = t;
      const int row = chunk >> 2;
      const int gg = (chunk & 3) ^ ((row >> 1) & 3);
      async_copy16(Wp + (size_t)(bn * 64 + row) * KDIM + kk + gg * 8,
                   Bs + buf * 2048 + chunk * 8);
    }
  };

  stage(0, 0);
  stage(1, 32);
  int buf = 0;
  for (int kk = 0; kk < KDIM; kk += 32) {
    if (kk + 64 < KDIM) {
      int nb = buf + 2; if (nb >= 3) nb -= 3;
      stage(nb, kk + 64);
      WAITCNT_VM(6);
    } else if (kk + 32 < KDIM) {
      WAITCNT_VM(3);
    } else {
      WAITCNT_VM(0);
    }
    RAW_BARRIER();

    frag8 aF[4], bF[2];
#pragma unroll
    for (int mi = 0; mi < 4; ++mi) {
      const int row = wm * 64 + mi * 16 + laneN;
      aF[mi] = ld_frag(As + buf * 4096 + row * 32 +
                       ((quad ^ ((row >> 1) & 3)) * 8));
    }
#pragma unroll
    for (int ni = 0; ni < 2; ++ni) {
      const int row = wn * 32 + ni * 16 + laneN;
      bF[ni] = ld_frag(Bs + buf * 2048 + row * 32 +
                       ((quad ^ ((row >> 1) & 3)) * 8));
    }
#pragma unroll
    for (int mi = 0; mi < 4; ++mi)
#pragma unroll
      for (int ni = 0; ni < 2; ++ni)
        acc[mi][ni] = mfma_f16(aF[mi], bF[ni], acc[mi][ni]);
    RAW_BARRIER();
    buf = buf + 1 == 3 ? 0 : buf + 1;
  }

#pragma unroll
  for (int mi = 0; mi < 4; ++mi)
#pragma unroll
    for (int ni = 0; ni < 2; ++ni) {
      const int colg = bn * 64 + wn * 32 + ni * 16 + laneN;
      const float bb = bias[colg];
#pragma unroll
      for (int r = 0; r < 4; ++r) {
        const int rowg = bm * 128 + wm * 64 + mi * 16 + quad * 4 + r;
        Out[(size_t)rowg * 1024 + colg] = acc[mi][ni][r] + bb;
      }
    }
}

// ---------------------------------------------------------------------------
// Flash attention, fp16. RESTRUCTURED R9: 256 threads = 4 waves x 16 q =
// 64 q/block, 1024 blocks -> 4 independent barrier domains per CU (was 2
// lockstepped 512-thread blocks; MfmaUtil 22 / VALUBusy 45 / Occ 36 showed
// barrier serialization, not pipe saturation). LDS trimmed to exactly 40 KiB
// per block (4 x 40960 = 160 KiB/CU): P strip stride 72 -> 64 shorts with
// ROTATED k-block placement slot=(g+q)&7 — bank-balanced for both the b64
// packs (4 lanes / 8B window) and b128 frag reads (8 lanes / 16B window).
// Also: T13 defer-max (rescale only when max grows > 8 in exp2 domain;
// P <= 2^8 fits fp16) and tree-shaped max/sum reductions (shorter dep chain).
// ---------------------------------------------------------------------------
__global__ __launch_bounds__(256, 4)
void attn(const short* __restrict__ Qf, const short* __restrict__ Kf,
          const short* __restrict__ Vt_, short* __restrict__ Ow) {
  __shared__ short Ks[2 * 4096];     // 2 x 64k x 64d
  __shared__ short Vts[2 * 4096];    // 2 x 64d x 64k
  __shared__ short Ps[4][16 * 64];   // per-wave P strip [q][k], stride 64

  // XCD-locality: 1024 blocks = 8 XCDs x 4 (h,b) pairs x 32 q-tiles of 64
  const int blk = blockIdx.x;
  const int xcd = blk & 7, local = blk >> 3;     // local 0..127
  const int pair = xcd * 4 + (local >> 5);       // 0..31
  const int h = pair & 15, b = pair >> 4, qt = local & 31;
  const size_t head = ((size_t)b * H_ + h) * (size_t)S_ * HD_;

  const int t = threadIdx.x;
  const int wave = t >> 6, lane = t & 63;
  const int laneN = lane & 15, quad = lane >> 4;

  // Q frags (B-operand); wave owns 16 q rows
  frag8 qf[2];
  {
    const size_t row = (size_t)qt * 64 + wave * 16 + laneN;
#pragma unroll
    for (int half = 0; half < 2; ++half)
      qf[half] = ld_frag(Qf + head + row * HD_ + half * 32 + quad * 8);
  }

  f32x4 o[4];          // O^T: row d = dt*16+quad*4+r, col q = laneN
  float m_r = -1e30f, l_r = 0.f;
#pragma unroll
  for (int i = 0; i < 4; ++i)
#pragma unroll
    for (int j = 0; j < 4; ++j) o[i][j] = 0.f;

  auto stage = [&](int buf, int kt) {   // 4 asyncs/thread
#pragma unroll
    for (int j = 0; j < 2; ++j) {
      const int chunk = j * 256 + t;    // 0..511
      const int row = chunk >> 3;       // 0..63
      const int g = (chunk & 7) ^ (row & 7);
      const int ldsoff = buf * 4096 + chunk * 8;
      async_copy16(Kf + head + (size_t)(kt * 64 + row) * HD_ + g * 8,
                   Ks + ldsoff);
      async_copy16(Vt_ + head + (size_t)row * S_ + kt * 64 + g * 8,
                   Vts + ldsoff);
    }
  };

  // per-lane invariant P-strip addresses (rotation slot = (blk + q) & 7)
  short* const pwr = &Ps[wave][0] + laneN * 64;
  const int rd0 = ((quad + laneN) & 7) * 8;        // blocks 0..3  (k 0..31)
  const int rd1 = (((quad + 4) + laneN) & 7) * 8;  // blocks 4..7  (k 32..63)

  stage(0, 0);
  int buf = 0;
  for (int kt = 0; kt < 32; ++kt, buf ^= 1) {
    if (kt + 1 < 32) {
      stage(buf ^ 1, kt + 1);
      WAITCNT_VM(4);
    } else {
      WAITCNT_VM(0);
    }
    RAW_BARRIER();

    const short* Kb = Ks + buf * 4096;
    const short* Vb = Vts + buf * 4096;

    // Vt frags (A-operand of PV): rows d = dt*16+laneN
    frag8 vf[4][2];
#pragma unroll
    for (int dt = 0; dt < 4; ++dt) {
      const int row = dt * 16 + laneN;
#pragma unroll
      for (int half = 0; half < 2; ++half)
        vf[dt][half] = ld_frag(Vb + row * 64 +
                               (((half * 4 + quad) ^ (row & 7)) * 8));
    }

    // S^T = K.Q^T: per lane 16 logits for q=laneN, k = nt*16+quad*4+r
    f32x4 s[4];
#pragma unroll
    for (int nt = 0; nt < 4; ++nt) {
      const int row = nt * 16 + laneN;
      frag8 k0 = ld_frag(Kb + row * 64 + ((quad ^ (row & 7)) * 8));
      frag8 k1 = ld_frag(Kb + row * 64 + (((quad + 4) ^ (row & 7)) * 8));
      f32x4 acc;
#pragma unroll
      for (int j = 0; j < 4; ++j) acc[j] = 0.f;
      acc = mfma_f16(k0, qf[0], acc);
      acc = mfma_f16(k1, qf[1], acc);
      s[nt] = acc;
    }

    // online softmax (exp2 domain), tree reduce + defer-max (THR=8)
    {
      float mt[4];
#pragma unroll
      for (int nt = 0; nt < 4; ++nt)
        mt[nt] = fmaxf(fmaxf(s[nt][0], s[nt][1]), fmaxf(s[nt][2], s[nt][3]));
      float mx = fmaxf(fmaxf(mt[0], mt[1]), fmaxf(mt[2], mt[3]));
      mx = fmaxf(mx, __shfl_xor(mx, 16));
      mx = fmaxf(mx, __shfl_xor(mx, 32));
      if (__any(mx > m_r + 8.f)) {     // wave-uniform: rescale rarely
        const float mn = fmaxf(m_r, mx);
        const float al = fast_exp2(m_r - mn);
        m_r = mn;
        l_r *= al;
#pragma unroll
        for (int dt = 0; dt < 4; ++dt)
#pragma unroll
          for (int r = 0; r < 4; ++r) o[dt][r] *= al;
      }
      float rt[4];
#pragma unroll
      for (int nt = 0; nt < 4; ++nt) {
        const float p0 = fast_exp2(s[nt][0] - m_r);
        const float p1 = fast_exp2(s[nt][1] - m_r);
        const float p2 = fast_exp2(s[nt][2] - m_r);
        const float p3 = fast_exp2(s[nt][3] - m_r);
        s[nt][0] = p0; s[nt][1] = p1; s[nt][2] = p2; s[nt][3] = p3;
        rt[nt] = (p0 + p1) + (p2 + p3);
      }
      float rs = (rt[0] + rt[1]) + (rt[2] + rt[3]);
      rs += __shfl_xor(rs, 16);
      rs += __shfl_xor(rs, 32);
      l_r += rs;
    }

    // P pack: 4 consecutive k per nt -> one b64 write at rotated slot
#pragma unroll
    for (int nt = 0; nt < 4; ++nt) {
      i32x2 w;
      w[0] = pk2h(s[nt][0], s[nt][1]);
      w[1] = pk2h(s[nt][2], s[nt][3]);
      const int g = nt * 2 + (quad >> 1);          // k-block index
      const int slot = (g + laneN) & 7;            // rotated placement
      *(i32x2*)(pwr + slot * 8 + (quad & 1) * 4) = w;
    }
    // B-operand P frags (per-wave strip; in-order DS within a wave)
    const frag8 p0 = ld_frag(pwr + rd0);
    const frag8 p1 = ld_frag(pwr + rd1);
#pragma unroll
    for (int dt = 0; dt < 4; ++dt) {
      o[dt] = mfma_f16(vf[dt][0], p0, o[dt]);
      o[dt] = mfma_f16(vf[dt][1], p1, o[dt]);
    }
    RAW_BARRIER();
  }

  // epilogue: O^T -> Ow[B,S,D] fp16; lane owns q, 4 consecutive d per dt
  {
    const float inv = 1.0f / l_r;
    const int sg = qt * 64 + wave * 16 + laneN;
    short* dst = Ow + ((size_t)b * S_ + sg) * D_ + h * HD_;
#pragma unroll
    for (int dt = 0; dt < 4; ++dt) {
      short pk[4] = { f2h(o[dt][0] * inv), f2h(o[dt][1] * inv),
                      f2h(o[dt][2] * inv), f2h(o[dt][3] * inv) };
      i32x2 w; __builtin_memcpy(&w, pk, 8);
      *(i32x2*)(dst + dt * 16 + quad * 4) = w;
    }
  }
}

// ---------------------------------------------------------------------------
extern "C" void kernel_launch(void* const* d_in, const int* in_sizes, int n_in,
                              void* d_out, int out_size, void* d_ws, size_t ws_size,
                              hipStream_t stream) {
  const float* q  = (const float*)d_in[0];
  const float* k  = (const float*)d_in[1];
  const float* v  = (const float*)d_in[2];
  const float* Wq = (const float*)d_in[3];
  const float* bq = (const float*)d_in[4];
  const float* Wk = (const float*)d_in[5];
  const float* bk = (const float*)d_in[6];
  const float* Wv = (const float*)d_in[7];
  const float* bv = (const float*)d_in[8];
  const float* Wo = (const float*)d_in[9];
  const float* bo = (const float*)d_in[10];

  const size_t NTOK = (size_t)B_ * S_ * D_;   // 4,194,304
  const size_t NW   = (size_t)D_ * D_;        // 1,048,576
  short* p = (short*)d_ws;
  short* qh = p; p += NTOK;  short* kh = p; p += NTOK;  short* vh = p; p += NTOK;
  short* wq = p; p += NW;    short* wk = p; p += NW;
  short* wv = p; p += NW;    short* wo = p; p += NW;
  short* Qf = p; p += NTOK;  short* Kf = p; p += NTOK;
  short* Vt = p; p += NTOK;  short* Ow = p; p += NTOK;

  dim3 blk(256);

  conv_all<<<8192, blk, 0, stream>>>(q, k, v, Wq, Wk, Wv, Wo,
                                     qh, kh, vh, wq, wk, wv, wo);

  const float QS = 11.541560327111707f;  // 8 * log2(e): exp2-domain softmax
  gemm_qkv<<<768, blk, 0, stream>>>(qh, kh, vh, wq, wk, wv, bq, bk, bv,
                                    Qf, Kf, Vt, QS);

  attn<<<1024, dim3(256), 0, stream>>>(Qf, Kf, Vt, Ow);

  gemm_out<<<512, blk, 0, stream>>>(Ow, wo, bo, (float*)d_out);
}